// Round 1
// baseline (29.949 us; speedup 1.0000x reference)
//
#include <hip/hip_runtime.h>
#include <math.h>

// Tiny MLP: 6 -> 8 (relu) -> 4 (relu) -> 2 (relu) -> 1, then softplus.
// Memory-bound streaming op: 4 rows per thread, float4 I/O.

__device__ __forceinline__ float softplus_f(float z) {
    // stable: max(z,0) + log1p(exp(-|z|))  == logaddexp(z, 0)
    return fmaxf(z, 0.0f) + log1pf(expf(-fabsf(z)));
}

__global__ __launch_bounds__(256) void encoder_mlp_kernel(
    const float* __restrict__ x,
    const float* __restrict__ W1, const float* __restrict__ b1,
    const float* __restrict__ W7, const float* __restrict__ b7,
    const float* __restrict__ W8, const float* __restrict__ b8,
    const float* __restrict__ W9, const float* __restrict__ b9,
    float* __restrict__ out, int n_rows)
{
    const int t = blockIdx.x * blockDim.x + threadIdx.x;
    const long long row0 = (long long)t * 4;
    if (row0 >= n_rows) return;

    float xr[4][6];
    bool full_quad = (row0 + 4 <= n_rows);

    if (full_quad) {
        // 4 rows = 24 floats = 6 x float4, 16B-aligned (t*96 bytes).
        const float4* xin = reinterpret_cast<const float4*>(x) + (size_t)t * 6;
        float4 v0 = xin[0], v1 = xin[1], v2 = xin[2],
               v3 = xin[3], v4 = xin[4], v5 = xin[5];
        xr[0][0] = v0.x; xr[0][1] = v0.y; xr[0][2] = v0.z; xr[0][3] = v0.w; xr[0][4] = v1.x; xr[0][5] = v1.y;
        xr[1][0] = v1.z; xr[1][1] = v1.w; xr[1][2] = v2.x; xr[1][3] = v2.y; xr[1][4] = v2.z; xr[1][5] = v2.w;
        xr[2][0] = v3.x; xr[2][1] = v3.y; xr[2][2] = v3.z; xr[2][3] = v3.w; xr[2][4] = v4.x; xr[2][5] = v4.y;
        xr[3][0] = v4.z; xr[3][1] = v4.w; xr[3][2] = v5.x; xr[3][3] = v5.y; xr[3][4] = v5.z; xr[3][5] = v5.w;
    } else {
        #pragma unroll
        for (int r = 0; r < 4; ++r) {
            long long row = row0 + r;
            #pragma unroll
            for (int k = 0; k < 6; ++k)
                xr[r][k] = (row < n_rows) ? x[row * 6 + k] : 0.0f;
        }
    }

    float res[4];
    #pragma unroll
    for (int r = 0; r < 4; ++r) {
        // layer 1: 6 -> 8, relu
        float h1[8];
        #pragma unroll
        for (int j = 0; j < 8; ++j) {
            float acc = b1[j];
            #pragma unroll
            for (int k = 0; k < 6; ++k) acc = fmaf(W1[j * 6 + k], xr[r][k], acc);
            h1[j] = fmaxf(acc, 0.0f);
        }
        // layer 7: 8 -> 4, relu
        float h7[4];
        #pragma unroll
        for (int j = 0; j < 4; ++j) {
            float acc = b7[j];
            #pragma unroll
            for (int k = 0; k < 8; ++k) acc = fmaf(W7[j * 8 + k], h1[k], acc);
            h7[j] = fmaxf(acc, 0.0f);
        }
        // layer 8: 4 -> 2, relu
        float h8[2];
        #pragma unroll
        for (int j = 0; j < 2; ++j) {
            float acc = b8[j];
            #pragma unroll
            for (int k = 0; k < 4; ++k) acc = fmaf(W8[j * 4 + k], h7[k], acc);
            h8[j] = fmaxf(acc, 0.0f);
        }
        // layer 9: 2 -> 1, softplus
        float z = fmaf(W9[0], h8[0], fmaf(W9[1], h8[1], b9[0]));
        res[r] = softplus_f(z);
    }

    if (full_quad) {
        float4 o;
        o.x = res[0]; o.y = res[1]; o.z = res[2]; o.w = res[3];
        reinterpret_cast<float4*>(out)[t] = o;
    } else {
        #pragma unroll
        for (int r = 0; r < 4; ++r) {
            long long row = row0 + r;
            if (row < n_rows) out[row] = res[r];
        }
    }
}

extern "C" void kernel_launch(void* const* d_in, const int* in_sizes, int n_in,
                              void* d_out, int out_size, void* d_ws, size_t ws_size,
                              hipStream_t stream) {
    const float* x  = (const float*)d_in[0];
    const float* W1 = (const float*)d_in[1];
    const float* b1 = (const float*)d_in[2];
    const float* W7 = (const float*)d_in[3];
    const float* b7 = (const float*)d_in[4];
    const float* W8 = (const float*)d_in[5];
    const float* b8 = (const float*)d_in[6];
    const float* W9 = (const float*)d_in[7];
    const float* b9 = (const float*)d_in[8];
    float* out = (float*)d_out;

    const int n_rows = in_sizes[0] / 6;               // 4194304
    const int n_threads = (n_rows + 3) / 4;           // 4 rows per thread
    const int block = 256;
    const int grid = (n_threads + block - 1) / block; // 4096 blocks

    encoder_mlp_kernel<<<grid, block, 0, stream>>>(
        x, W1, b1, W7, b7, W8, b8, W9, b9, out, n_rows);
}

// Round 2
// 24.690 us; speedup vs baseline: 1.2130x; 1.2130x over previous
//
#include <hip/hip_runtime.h>
#include <math.h>

// Tiny MLP: 6 -> 8 (relu) -> 4 (relu) -> 2 (relu) -> 1, then softplus.
// Memory-bound streaming op: 4 rows per thread, float4 I/O.
// R1: replace library expf/log1pf with hardware-native __expf/__logf
// (v_exp_f32 / v_log_f32) — absmax threshold 1.86e-2 gives huge headroom.

__device__ __forceinline__ float softplus_fast(float z) {
    // stable: max(z,0) + log(1 + exp(-|z|)), native transcendentals
    float e = __expf(-fabsf(z));            // v_exp_f32 path
    return fmaxf(z, 0.0f) + __logf(1.0f + e); // v_log_f32 path
}

__global__ __launch_bounds__(256) void encoder_mlp_kernel(
    const float* __restrict__ x,
    const float* __restrict__ W1, const float* __restrict__ b1,
    const float* __restrict__ W7, const float* __restrict__ b7,
    const float* __restrict__ W8, const float* __restrict__ b8,
    const float* __restrict__ W9, const float* __restrict__ b9,
    float* __restrict__ out, int n_rows)
{
    const int t = blockIdx.x * blockDim.x + threadIdx.x;
    const long long row0 = (long long)t * 4;
    if (row0 >= n_rows) return;

    float xr[4][6];
    bool full_quad = (row0 + 4 <= n_rows);

    if (full_quad) {
        // 4 rows = 24 floats = 6 x float4, 16B-aligned (t*96 bytes).
        const float4* xin = reinterpret_cast<const float4*>(x) + (size_t)t * 6;
        float4 v0 = xin[0], v1 = xin[1], v2 = xin[2],
               v3 = xin[3], v4 = xin[4], v5 = xin[5];
        xr[0][0] = v0.x; xr[0][1] = v0.y; xr[0][2] = v0.z; xr[0][3] = v0.w; xr[0][4] = v1.x; xr[0][5] = v1.y;
        xr[1][0] = v1.z; xr[1][1] = v1.w; xr[1][2] = v2.x; xr[1][3] = v2.y; xr[1][4] = v2.z; xr[1][5] = v2.w;
        xr[2][0] = v3.x; xr[2][1] = v3.y; xr[2][2] = v3.z; xr[2][3] = v3.w; xr[2][4] = v4.x; xr[2][5] = v4.y;
        xr[3][0] = v4.z; xr[3][1] = v4.w; xr[3][2] = v5.x; xr[3][3] = v5.y; xr[3][4] = v5.z; xr[3][5] = v5.w;
    } else {
        #pragma unroll
        for (int r = 0; r < 4; ++r) {
            long long row = row0 + r;
            #pragma unroll
            for (int k = 0; k < 6; ++k)
                xr[r][k] = (row < n_rows) ? x[row * 6 + k] : 0.0f;
        }
    }

    float res[4];
    #pragma unroll
    for (int r = 0; r < 4; ++r) {
        // layer 1: 6 -> 8, relu
        float h1[8];
        #pragma unroll
        for (int j = 0; j < 8; ++j) {
            float acc = b1[j];
            #pragma unroll
            for (int k = 0; k < 6; ++k) acc = fmaf(W1[j * 6 + k], xr[r][k], acc);
            h1[j] = fmaxf(acc, 0.0f);
        }
        // layer 7: 8 -> 4, relu
        float h7[4];
        #pragma unroll
        for (int j = 0; j < 4; ++j) {
            float acc = b7[j];
            #pragma unroll
            for (int k = 0; k < 8; ++k) acc = fmaf(W7[j * 8 + k], h1[k], acc);
            h7[j] = fmaxf(acc, 0.0f);
        }
        // layer 8: 4 -> 2, relu
        float h8[2];
        #pragma unroll
        for (int j = 0; j < 2; ++j) {
            float acc = b8[j];
            #pragma unroll
            for (int k = 0; k < 4; ++k) acc = fmaf(W8[j * 4 + k], h7[k], acc);
            h8[j] = fmaxf(acc, 0.0f);
        }
        // layer 9: 2 -> 1, softplus
        float z = fmaf(W9[0], h8[0], fmaf(W9[1], h8[1], b9[0]));
        res[r] = softplus_fast(z);
    }

    if (full_quad) {
        float4 o;
        o.x = res[0]; o.y = res[1]; o.z = res[2]; o.w = res[3];
        reinterpret_cast<float4*>(out)[t] = o;
    } else {
        #pragma unroll
        for (int r = 0; r < 4; ++r) {
            long long row = row0 + r;
            if (row < n_rows) out[row] = res[r];
        }
    }
}

extern "C" void kernel_launch(void* const* d_in, const int* in_sizes, int n_in,
                              void* d_out, int out_size, void* d_ws, size_t ws_size,
                              hipStream_t stream) {
    const float* x  = (const float*)d_in[0];
    const float* W1 = (const float*)d_in[1];
    const float* b1 = (const float*)d_in[2];
    const float* W7 = (const float*)d_in[3];
    const float* b7 = (const float*)d_in[4];
    const float* W8 = (const float*)d_in[5];
    const float* b8 = (const float*)d_in[6];
    const float* W9 = (const float*)d_in[7];
    const float* b9 = (const float*)d_in[8];
    float* out = (float*)d_out;

    const int n_rows = in_sizes[0] / 6;               // 4194304
    const int n_threads = (n_rows + 3) / 4;           // 4 rows per thread
    const int block = 256;
    const int grid = (n_threads + block - 1) / block; // 4096 blocks

    encoder_mlp_kernel<<<grid, block, 0, stream>>>(
        x, W1, b1, W7, b7, W8, b8, W9, b9, out, n_rows);
}